// Round 7
// baseline (206.261 us; speedup 1.0000x reference)
//
#include <hip/hip_runtime.h>
#include <math.h>

// MuLUT ConvBlock, round 7: same validated structure as round 6 (weights in
// 160KB LDS, acts in VGPRs, permuted-K fragments, hi/lo bf16 split) but
// 1024 threads/block (16 waves -> 4 waves/SIMD) for 2x latency hiding.
// Biases via wave-uniform s_loads + cndmask select (no VGPR hoard, no vmcnt
// drain). Out-zeroing merged into prep kernel (one less graph node).

typedef short bf16x8 __attribute__((ext_vector_type(8)));
typedef short short4v __attribute__((ext_vector_type(4)));
typedef float f32x4  __attribute__((ext_vector_type(4)));

__device__ __forceinline__ short f2bf_bits(float v) {
    union { float f; unsigned u; } x; x.f = v;
    unsigned r = x.u + 0x7FFFu + ((x.u >> 16) & 1u);   // RNE
    return (short)(r >> 16);
}
__device__ __forceinline__ float bf2f(short s) {
    union { unsigned u; float f; } x; x.u = ((unsigned)(unsigned short)s) << 16;
    return x.f;
}

// ---------------------------------------------------------------------------
// prep: weights -> per-branch fragment image in d_ws (identical to round 6),
// plus W1 repack and d_out zeroing (blocks 136..167).
// ---------------------------------------------------------------------------
__global__ void prep_weights(const float* __restrict__ W1, const float* __restrict__ W2,
                             const float* __restrict__ W3, const float* __restrict__ W4,
                             const float* __restrict__ W5, const float* __restrict__ W6,
                             short* __restrict__ wsw, float* __restrict__ w1p,
                             float* __restrict__ outz)
{
    if (blockIdx.x < 135) {
        const int t = blockIdx.x * 256 + threadIdx.x;   // 0..34559
        const int frag = t >> 6, lane = t & 63;
        const int b = frag / 90, slot = frag % 90;
        const int kqh = lane >> 4, rowl = lane & 15;
        const float* src; int K, kb, m; bool head = false;
        if (slot < 8)       { src = W2; K = 64;  kb = slot >> 2;        m = slot & 3; }
        else if (slot < 24) { src = W3; K = 128; kb = (slot - 8) >> 2;  m = slot & 3; }
        else if (slot < 48) { src = W4; K = 192; kb = (slot - 24) >> 2; m = slot & 3; }
        else if (slot < 80) { src = W5; K = 256; kb = (slot - 48) >> 2; m = slot & 3; }
        else                { src = W6; K = 320; kb = slot - 80; m = 0; head = true; }
        short* hi = wsw + (size_t)b * 92160 + slot * 1024 + (lane << 3);
        short* lo = hi + 512;
        #pragma unroll
        for (int j = 0; j < 8; ++j) {
            const int k = kb * 32 + ((j & 4) ? 16 : 0) + kqh * 4 + (j & 3);
            float v;
            if (!head) v = src[(size_t)(b * 64 + m * 16 + rowl) * K + k];
            else       v = (rowl < 8) ? src[(size_t)(b * 8 + rowl) * 320 + k] : 0.0f;
            const short h = f2bf_bits(v);
            hi[j] = h;
            lo[j] = f2bf_bits(v - bf2f(h));
        }
    } else if (blockIdx.x == 135) {
        for (int d = threadIdx.x; d < 6912; d += 256) {
            const int bq = d / 288, rem = d % 288;
            const int it2 = rem >> 4, s16 = (rem >> 2) & 3, tt = rem & 3;
            const int b = bq >> 2, kq = bq & 3;
            const int img = it2 / 9, tap = it2 % 9;
            w1p[d] = W1[(size_t)((b * 64 + s16 * 16 + kq * 4 + tt) * 2 + img) * 9 + tap];
        }
    } else {
        // zero d_out: 32 blocks x 256 threads x 8 floats = 65536 floats
        const int i = ((blockIdx.x - 136) * 256 + (int)threadIdx.x) * 8;
        f32x4 z = {0.f, 0.f, 0.f, 0.f};
        *(f32x4*)(outz + i)     = z;
        *(f32x4*)(outz + i + 4) = z;
    }
}

// ---------------------------------------------------------------------------
__device__ __forceinline__ void pack_kb(const f32x4 a, const f32x4 bq,
                                        bf16x8* ph, bf16x8* pl) {
    bf16x8 h, l;
    #pragma unroll
    for (int e = 0; e < 4; ++e) {
        float v = fmaxf(a[e], 0.0f);
        short hs = f2bf_bits(v);
        h[e] = hs; l[e] = f2bf_bits(v - bf2f(hs));
        float v2 = fmaxf(bq[e], 0.0f);
        short hs2 = f2bf_bits(v2);
        h[4 + e] = hs2; l[4 + e] = f2bf_bits(v2 - bf2f(hs2));
    }
    *ph = h; *pl = l;
}

// wave-uniform bias pointer (s_load) -> per-lane select by kq (3 cndmask)
__device__ __forceinline__ float sel4(int kq, const float* __restrict__ p) {
    const float b0 = p[0], b1 = p[4], b2 = p[8], b3 = p[12];
    const float lo = (kq & 1) ? b1 : b0;
    const float hi = (kq & 1) ? b3 : b2;
    return (kq & 2) ? hi : lo;
}

#define ASM_VMCNT(N) asm volatile("s_waitcnt vmcnt(" #N ")" ::: "memory")

#define DENSE_STAGE(KB_IN, SLOT0, BPTR, OUTKB)                                          \
  {                                                                                      \
    f32x4 sacc[4];                                                                       \
    _Pragma("unroll") for (int m = 0; m < 4; ++m)                                        \
      _Pragma("unroll") for (int rr = 0; rr < 4; ++rr) sacc[m][rr] = 0.f;                \
    _Pragma("unroll") for (int kb = 0; kb < KB_IN; ++kb) {                               \
      _Pragma("unroll") for (int m = 0; m < 4; ++m) {                                    \
        const int so = (SLOT0 + kb * 4 + m) * 1024 + lane8;                              \
        bf16x8 ah = *(const bf16x8*)&wlds[so];                                           \
        bf16x8 al = *(const bf16x8*)&wlds[so + 512];                                     \
        sacc[m] = __builtin_amdgcn_mfma_f32_16x16x32_bf16(ah, act_h[kb], sacc[m], 0, 0, 0); \
        sacc[m] = __builtin_amdgcn_mfma_f32_16x16x32_bf16(ah, act_l[kb], sacc[m], 0, 0, 0); \
        sacc[m] = __builtin_amdgcn_mfma_f32_16x16x32_bf16(al, act_h[kb], sacc[m], 0, 0, 0); \
      }                                                                                  \
    }                                                                                    \
    _Pragma("unroll") for (int m = 0; m < 4; ++m)                                        \
      _Pragma("unroll") for (int rr = 0; rr < 4; ++rr)                                   \
        sacc[m][rr] += sel4(kq, BPTR + m * 16 + rr);                                     \
    pack_kb(sacc[0], sacc[1], &act_h[OUTKB], &act_l[OUTKB]);                             \
    pack_kb(sacc[2], sacc[3], &act_h[OUTKB + 1], &act_l[OUTKB + 1]);                     \
  }

__global__ __launch_bounds__(1024) void mulut_main(
    const float* __restrict__ x, const float* __restrict__ px_,
    const float* __restrict__ B1, const float* __restrict__ B2,
    const float* __restrict__ B3, const float* __restrict__ B4,
    const float* __restrict__ B5, const float* __restrict__ B6,
    const short* __restrict__ wsw, const float* __restrict__ w1p,
    float* __restrict__ out)
{
    __shared__ short wlds[81920];   // 160 KB

    const int blk = blockIdx.x;             // b*128 + n*16 + q
    const int q   = blk & 15;
    const int n   = (blk >> 4) & 7;
    const int b   = blk >> 7;
    const int c   = (b >= 3) ? 1 : 0;
    const int r   = n >> 1;
    const int batch = n & 1;

    const int tid   = threadIdx.x;
    const int w     = tid >> 6;            // 0..15
    const int lane  = tid & 63;
    const int col   = lane & 15;
    const int kq    = lane >> 4;
    const int lane8 = lane << 3;

    const int row = q * 4 + (w >> 2);      // 4 rows/strip, 4 waves per row
    const int px  = (w & 3) * 16 + col;    // this lane's pixel column

    const char* wsb = (const char*)(wsw + (size_t)b * 92160);

    bf16x8 act_h[10];
    bf16x8 act_l[10];

    // ================= conv 3x3 (fp32 VALU, exact) ==========================
    {
        const float* img0 = x   + ((batch * 2 + c) << 12);
        const float* img1 = px_ + ((batch * 2 + c) << 12);
        float g[2][9];
        #pragma unroll
        for (int di = 0; di < 3; ++di) {
            const int ii = min(row + di, 63);
            #pragma unroll
            for (int dj = 0; dj < 3; ++dj) {
                const int jj = min(px + dj, 63);
                int si, sj;
                if      (r == 0) { si = ii;      sj = jj;      }
                else if (r == 1) { si = jj;      sj = 63 - ii; }
                else if (r == 2) { si = 63 - ii; sj = 63 - jj; }
                else             { si = 63 - jj; sj = ii;      }
                g[0][di * 3 + dj] = img0[si * 64 + sj];
                g[1][di * 3 + dj] = img1[si * 64 + sj];
            }
        }

        f32x4 accc[4];
        #pragma unroll
        for (int s16 = 0; s16 < 4; ++s16)
            #pragma unroll
            for (int t = 0; t < 4; ++t) accc[s16][t] = 0.f;

        const f32x4* wp0 = (const f32x4*)&w1p[(b * 4 + kq) * 288];
        #pragma unroll
        for (int it = 0; it < 18; ++it) {
            const float gv = g[it / 9][it % 9];
            #pragma unroll
            for (int s16 = 0; s16 < 4; ++s16) {
                const f32x4 w4 = wp0[it * 4 + s16];
                #pragma unroll
                for (int t = 0; t < 4; ++t)
                    accc[s16][t] = fmaf(gv, w4[t], accc[s16][t]);
            }
        }
        #pragma unroll
        for (int m = 0; m < 4; ++m)
            #pragma unroll
            for (int rr = 0; rr < 4; ++rr)
                accc[m][rr] += sel4(kq, B1 + b * 64 + m * 16 + rr);
        pack_kb(accc[0], accc[1], &act_h[0], &act_l[0]);
        pack_kb(accc[2], accc[3], &act_h[1], &act_l[1]);
    }

    __builtin_amdgcn_sched_barrier(0);

    // ================= dense weight staging: 10 x 16KB chunks ===============
    #pragma unroll
    for (int ck = 0; ck < 10; ++ck) {
        const unsigned off = ck * 16384 + w * 1024;
        __builtin_amdgcn_global_load_lds((const unsigned*)(wsb + off + lane * 16),
                                         (unsigned*)&wlds[off >> 1], 16, 0, 0);
    }
    __builtin_amdgcn_sched_barrier(0);

    // stage 1 needs chunk 0 -> 9 newer may remain
    ASM_VMCNT(9);
    __builtin_amdgcn_s_barrier();
    DENSE_STAGE(2, 0, B2 + b * 64, 2)

    // stage 2 needs chunks 1-2
    ASM_VMCNT(7);
    __builtin_amdgcn_s_barrier();
    DENSE_STAGE(4, 8, B3 + b * 64, 4)

    // s1/s2 LDS region free -> overlay head weights (20KB @ LDS 0)
    __builtin_amdgcn_s_barrier();
    {
        const unsigned l0 = w * 1024;
        __builtin_amdgcn_global_load_lds((const unsigned*)(wsb + 163840 + l0 + lane * 16),
                                         (unsigned*)&wlds[l0 >> 1], 16, 0, 0);
        const unsigned l1 = 16384 + w * 256;
        __builtin_amdgcn_global_load_lds((const unsigned*)(wsb + 163840 + l1 + lane * 4),
                                         (unsigned*)&wlds[l1 >> 1], 4, 0, 0);
    }
    __builtin_amdgcn_sched_barrier(0);

    // stage 3 needs chunks 3-5: newer = chunks 6-9 + 2 head
    ASM_VMCNT(6);
    __builtin_amdgcn_s_barrier();
    DENSE_STAGE(6, 24, B4 + b * 64, 6)

    // stage 4 needs chunks 6-9: newer = 2 head
    ASM_VMCNT(2);
    __builtin_amdgcn_s_barrier();
    DENSE_STAGE(8, 48, B5 + b * 64, 8)

    // head needs its 2 chunks
    ASM_VMCNT(0);
    __builtin_amdgcn_s_barrier();

    // ================= head (M=16 padded, K=320) ============================
    f32x4 hacc;
    #pragma unroll
    for (int rr = 0; rr < 4; ++rr) hacc[rr] = 0.f;
    #pragma unroll
    for (int kb = 0; kb < 10; ++kb) {
        const int so = kb * 1024 + lane8;
        bf16x8 ah = *(const bf16x8*)&wlds[so];
        bf16x8 al = *(const bf16x8*)&wlds[so + 512];
        hacc = __builtin_amdgcn_mfma_f32_16x16x32_bf16(ah, act_h[kb], hacc, 0, 0, 0);
        hacc = __builtin_amdgcn_mfma_f32_16x16x32_bf16(ah, act_l[kb], hacc, 0, 0, 0);
        hacc = __builtin_amdgcn_mfma_f32_16x16x32_bf16(al, act_h[kb], hacc, 0, 0, 0);
    }
    #pragma unroll
    for (int rr = 0; rr < 4; ++rr) {
        const float h0 = B6[b * 8 + rr];
        const float h1 = B6[b * 8 + 4 + rr];
        hacc[rr] += (kq == 0) ? h0 : ((kq == 1) ? h1 : 0.f);
    }

    // ================= epilogue: shuffle + inv-rot + round(tanh*127) ========
    #pragma unroll
    for (int rr = 0; rr < 4; ++rr) {
        const int ch = kq * 4 + rr;
        if (ch < 8) {
            const int oc = ch >> 2;
            const int a  = (ch >> 1) & 1;
            const int bb = ch & 1;
            const int ip = 2 * row + a;
            const int jp = 2 * px + bb;
            int I, J;
            if      (r == 0) { I = ip;       J = jp;       }
            else if (r == 1) { I = jp;       J = 127 - ip; }
            else if (r == 2) { I = 127 - ip; J = 127 - jp; }
            else             { I = 127 - jp; J = ip;       }
            const float v = rintf(tanhf(hacc[rr]) * 127.0f);
            atomicAdd(out + (((batch * 2 + oc) << 14) + I * 128 + J), v * 0.5f);
        }
    }
}

extern "C" void kernel_launch(void* const* d_in, const int* in_sizes, int n_in,
                              void* d_out, int out_size, void* d_ws, size_t ws_size,
                              hipStream_t stream) {
    const float* x   = (const float*)d_in[0];
    const float* pxv = (const float*)d_in[1];
    const float* W1  = (const float*)d_in[2];
    const float* B1  = (const float*)d_in[3];
    const float* W2  = (const float*)d_in[4];
    const float* B2  = (const float*)d_in[5];
    const float* W3  = (const float*)d_in[6];
    const float* B3  = (const float*)d_in[7];
    const float* W4  = (const float*)d_in[8];
    const float* B4  = (const float*)d_in[9];
    const float* W5  = (const float*)d_in[10];
    const float* B5  = (const float*)d_in[11];
    const float* W6  = (const float*)d_in[12];
    const float* B6  = (const float*)d_in[13];
    float* out = (float*)d_out;

    short* wsw = (short*)d_ws;                       // 6 * 92160 shorts
    float* w1p = (float*)(wsw + 6 * 92160);          // 6912 floats

    prep_weights<<<dim3(168), dim3(256), 0, stream>>>(W1, W2, W3, W4, W5, W6,
                                                      wsw, w1p, out);
    mulut_main<<<dim3(768), dim3(1024), 0, stream>>>(
        x, pxv, B1, B2, B3, B4, B5, B6, wsw, w1p, out);
}

// Round 11
// 180.012 us; speedup vs baseline: 1.1458x; 1.1458x over previous
//
#include <hip/hip_runtime.h>
#include <math.h>

// MuLUT ConvBlock, round 8: 64KB LDS ping-pong weight streaming (2 blocks/CU,
// 4 waves/SIMD, no spills), acts in VGPRs (permuted-K fragments), hi/lo bf16
// split (3 MFMA/k-step). Coalesced prep via LDS transpose.
// Grid: 1536 blocks x 512 thr; block = (branch, image, 2-row strip); wave = 16px.

typedef short bf16x8 __attribute__((ext_vector_type(8)));
typedef float f32x4  __attribute__((ext_vector_type(4)));
typedef float f32x4g __attribute__((ext_vector_type(4)));

__device__ __forceinline__ short f2bf_bits(float v) {
    union { float f; unsigned u; } x; x.f = v;
    unsigned r = x.u + 0x7FFFu + ((x.u >> 16) & 1u);   // RNE
    return (short)(r >> 16);
}
__device__ __forceinline__ float bf2f(short s) {
    union { unsigned u; float f; } x; x.u = ((unsigned)(unsigned short)s) << 16;
    return x.f;
}

// ---------------------------------------------------------------------------
// prep: coalesced. Block 0..29 = (branch, stage): linear read of W tensor into
// LDS, scatter-read from LDS, coalesced fragment write. Block 30 = W1 repack.
// Blocks 31..62 = zero d_out.
// d_ws branch image: 92 slots x 2KB (hi 1KB | lo 1KB), stage-major:
// SlotBase = {0,8,24,48,80(head, padded to 12)}; slot = kb*4+m (head: kb).
// frag elem (lane,j): out_row = m*16+(lane&15),
//   k = kb*32 + (j&4?16:0) + (lane>>4)*4 + (j&3)    [permuted-K]
// ---------------------------------------------------------------------------
__global__ void prep_weights(const float* __restrict__ W1, const float* __restrict__ W2,
                             const float* __restrict__ W3, const float* __restrict__ W4,
                             const float* __restrict__ W5, const float* __restrict__ W6,
                             short* __restrict__ wsw, float* __restrict__ w1p,
                             float* __restrict__ outz)
{
    __shared__ float S[16384];   // 64KB
    const int blk = blockIdx.x, tid = threadIdx.x;

    if (blk < 30) {
        const int b = blk / 5, s = blk % 5;
        const float* Wsrc[5] = { W2, W3, W4, W5, W6 };
        const int rows = (s < 4) ? 64 : 8;
        const int K    = 64 * (s + 1);
        const int N    = rows * K;
        const int slotbase[5] = { 0, 8, 24, 48, 80 };
        const int nslots[5]   = { 8, 16, 24, 32, 12 };

        const float* src = Wsrc[s] + (size_t)b * N;
        for (int i = tid; i < (N >> 2); i += 256)
            *(f32x4g*)&S[i << 2] = *(const f32x4g*)&src[i << 2];
        __syncthreads();

        const int NS = nslots[s];
        for (int pp = tid; pp < NS * 64; pp += 256) {
            const int l    = pp >> 6;
            const int lane = pp & 63;
            const int kb   = (s < 4) ? (l >> 2) : l;
            const int m    = (s < 4) ? (l & 3) : 0;
            const int rowl = lane & 15;
            const int kqh  = lane >> 4;
            bf16x8 hv, lv;
            #pragma unroll
            for (int j = 0; j < 8; ++j) {
                const int k = kb * 32 + ((j & 4) ? 16 : 0) + kqh * 4 + (j & 3);
                float v;
                if (s < 4)                    v = S[(m * 16 + rowl) * K + k];
                else if (rowl < 8 && l < 10)  v = S[rowl * 320 + k];
                else                          v = 0.0f;
                const short h = f2bf_bits(v);
                hv[j] = h;
                lv[j] = f2bf_bits(v - bf2f(h));
            }
            short* dst = wsw + (size_t)b * 94208 + (slotbase[s] + l) * 1024 + (lane << 3);
            *(bf16x8*)dst         = hv;
            *(bf16x8*)(dst + 512) = lv;
        }
    } else if (blk == 30) {
        for (int d = tid; d < 6912; d += 256) {
            const int bq = d / 288, rem = d % 288;
            const int it2 = rem >> 4, s16 = (rem >> 2) & 3, tt = rem & 3;
            const int b = bq >> 2, kq = bq & 3;
            const int img = it2 / 9, tap = it2 % 9;
            w1p[d] = W1[(size_t)((b * 64 + s16 * 16 + kq * 4 + tt) * 2 + img) * 9 + tap];
        }
    } else {
        const int i = ((blk - 31) * 256 + tid) * 8;
        f32x4g z = {0.f, 0.f, 0.f, 0.f};
        *(f32x4g*)(outz + i)     = z;
        *(f32x4g*)(outz + i + 4) = z;
    }
}

// ---------------------------------------------------------------------------
__device__ __forceinline__ void pack_kb(const f32x4 a, const f32x4 bq,
                                        bf16x8* ph, bf16x8* pl) {
    bf16x8 h, l;
    #pragma unroll
    for (int e = 0; e < 4; ++e) {
        float v = fmaxf(a[e], 0.0f);
        short hs = f2bf_bits(v);
        h[e] = hs; l[e] = f2bf_bits(v - bf2f(hs));
        float v2 = fmaxf(bq[e], 0.0f);
        short hs2 = f2bf_bits(v2);
        h[4 + e] = hs2; l[4 + e] = f2bf_bits(v2 - bf2f(hs2));
    }
    *ph = h; *pl = l;
}

// wave-uniform bias (scalar loads) -> per-lane select by kq
__device__ __forceinline__ float sel4(int kq, const float* __restrict__ p) {
    const float b0 = p[0], b1 = p[4], b2 = p[8], b3 = p[12];
    const float lo = (kq & 1) ? b1 : b0;
    const float hi = (kq & 1) ? b3 : b2;
    return (kq & 2) ? hi : lo;
}

#define ASM_VMCNT(N) asm volatile("s_waitcnt vmcnt(" #N ")" ::: "memory")
#define MFMA(A, B, C) __builtin_amdgcn_mfma_f32_16x16x32_bf16(A, B, C, 0, 0, 0)

// issue one 32KB (NC=4) or 24KB (NC=3) piece: global slot SLOT0.., LDS base PB
#define ISSUE(SLOT0, NC, PB)                                                          \
  _Pragma("unroll") for (int c = 0; c < NC; ++c) {                                    \
    const unsigned lo_ = c * 8192u + w * 1024u;                                       \
    __builtin_amdgcn_global_load_lds(                                                 \
        (const unsigned*)(wsb + (SLOT0) * 2048 + lo_ + lane * 16),                    \
        (unsigned*)&wlds[(PB) + (lo_ >> 1)], 16, 0, 0);                               \
  }

// accumulate NKB k-blocks into SACC: acts act[A0..A0+NKB), weights at
// LDS base PB, slots SLOT0 + kb*4 + m
#define HALF(SACC, NKB, A0, PB, SLOT0)                                                \
  _Pragma("unroll") for (int kb = 0; kb < NKB; ++kb)                                  \
    _Pragma("unroll") for (int m = 0; m < 4; ++m) {                                   \
      const int so = (PB) + ((SLOT0) + kb * 4 + m) * 1024 + lane8;                    \
      bf16x8 ah = *(const bf16x8*)&wlds[so];                                          \
      bf16x8 al = *(const bf16x8*)&wlds[so + 512];                                    \
      SACC[m] = MFMA(ah, act_h[(A0) + kb], SACC[m]);                                  \
      SACC[m] = MFMA(ah, act_l[(A0) + kb], SACC[m]);                                  \
      SACC[m] = MFMA(al, act_h[(A0) + kb], SACC[m]);                                  \
    }

#define SACC_INIT(SACC)                                                               \
  _Pragma("unroll") for (int m = 0; m < 4; ++m)                                       \
    _Pragma("unroll") for (int rr = 0; rr < 4; ++rr) SACC[m][rr] = 0.f;

#define FINISH(SACC, BPTR, OUTKB)                                                     \
  _Pragma("unroll") for (int m = 0; m < 4; ++m)                                       \
    _Pragma("unroll") for (int rr = 0; rr < 4; ++rr)                                  \
      SACC[m][rr] += sel4(kq, (BPTR) + m * 16 + rr);                                  \
  pack_kb(SACC[0], SACC[1], &act_h[OUTKB], &act_l[OUTKB]);                            \
  pack_kb(SACC[2], SACC[3], &act_h[(OUTKB) + 1], &act_l[(OUTKB) + 1]);

__global__ __launch_bounds__(512, 4) void mulut_main(
    const float* __restrict__ x, const float* __restrict__ px_,
    const float* __restrict__ B1, const float* __restrict__ B2,
    const float* __restrict__ B3, const float* __restrict__ B4,
    const float* __restrict__ B5, const float* __restrict__ B6,
    const short* __restrict__ wsw, const float* __restrict__ w1p,
    float* __restrict__ out)
{
    __shared__ short wlds[32768];   // 64 KB: P0 @0, P1 @16384 (shorts)
    const int P1 = 16384;

    const int blk   = blockIdx.x;           // b*256 + n*32 + strip
    const int strip = blk & 31;
    const int n     = (blk >> 5) & 7;
    const int b     = blk >> 8;
    const int c     = (b >= 3) ? 1 : 0;
    const int r     = n >> 1;
    const int batch = n & 1;

    const int tid   = threadIdx.x;
    const int w     = tid >> 6;             // 0..7
    const int lane  = tid & 63;
    const int col   = lane & 15;
    const int kq    = lane >> 4;
    const int lane8 = lane << 3;

    const int row = strip * 2 + (w >> 2);
    const int px  = (w & 3) * 16 + col;

    const char* wsb = (const char*)(wsw + (size_t)b * 94208);

    bf16x8 act_h[10];
    bf16x8 act_l[10];

    // ================= conv 3x3 (fp32 VALU, exact) ==========================
    {
        const float* img0 = x   + ((batch * 2 + c) << 12);
        const float* img1 = px_ + ((batch * 2 + c) << 12);
        float g[2][9];
        #pragma unroll
        for (int di = 0; di < 3; ++di) {
            const int ii = min(row + di, 63);
            #pragma unroll
            for (int dj = 0; dj < 3; ++dj) {
                const int jj = min(px + dj, 63);
                int si, sj;
                if      (r == 0) { si = ii;      sj = jj;      }
                else if (r == 1) { si = jj;      sj = 63 - ii; }
                else if (r == 2) { si = 63 - ii; sj = 63 - jj; }
                else             { si = 63 - jj; sj = ii;      }
                g[0][di * 3 + dj] = img0[si * 64 + sj];
                g[1][di * 3 + dj] = img1[si * 64 + sj];
            }
        }
        f32x4 accc[4];
        SACC_INIT(accc)
        const f32x4* wp0 = (const f32x4*)&w1p[(b * 4 + kq) * 288];
        #pragma unroll
        for (int it = 0; it < 18; ++it) {
            const float gv = g[it / 9][it % 9];
            #pragma unroll
            for (int s16 = 0; s16 < 4; ++s16) {
                const f32x4 w4 = wp0[it * 4 + s16];
                #pragma unroll
                for (int t = 0; t < 4; ++t)
                    accc[s16][t] = fmaf(gv, w4[t], accc[s16][t]);
            }
        }
        FINISH(accc, B1 + b * 64, 0)
    }

    __builtin_amdgcn_sched_barrier(0);
    ISSUE(0, 4, 0)        // p1: s1(8 slots) + s2 kb0-1  -> P0
    ISSUE(16, 4, P1)      // p2: s2 kb2-3 + s3 kb0-1     -> P1
    __builtin_amdgcn_sched_barrier(0);

    ASM_VMCNT(4);                      // p1 landed
    __builtin_amdgcn_s_barrier();

    // C1: stage1 full + stage2 first half
    f32x4 sacc[4];
    SACC_INIT(sacc)
    HALF(sacc, 2, 0, 0, 0)             // s1 kb0-1 @P0 slots 0..7
    FINISH(sacc, B2 + b * 64, 2)
    f32x4 sacc2[4];
    SACC_INIT(sacc2)
    HALF(sacc2, 2, 0, 0, 8)            // s2 kb0-1 @P0 slots 8..15

    __builtin_amdgcn_s_barrier();      // all waves done reading P0
    __builtin_amdgcn_sched_barrier(0);
    ISSUE(32, 4, 0)       // p3: s3 kb2-5 -> P0
    __builtin_amdgcn_sched_barrier(0);
    ASM_VMCNT(4);                      // p2 landed
    __builtin_amdgcn_s_barrier();

    // C2: stage2 finish + stage3 first half
    HALF(sacc2, 2, 2, P1, 0)           // s2 kb2-3 @P1 slots 0..7
    FINISH(sacc2, B3 + b * 64, 4)
    SACC_INIT(sacc)
    HALF(sacc, 2, 0, P1, 8)            // s3 kb0-1 @P1 slots 8..15

    __builtin_amdgcn_s_barrier();      // done reading P1
    __builtin_amdgcn_sched_barrier(0);
    ISSUE(48, 4, P1)      // p4: s4 kb0-3 -> P1
    __builtin_amdgcn_sched_barrier(0);
    ASM_VMCNT(4);                      // p3 landed
    __builtin_amdgcn_s_barrier();

    // C3: stage3 finish
    HALF(sacc, 4, 2, 0, 0)             // s3 kb2-5 @P0 slots 0..15
    FINISH(sacc, B4 + b * 64, 6)

    __builtin_amdgcn_s_barrier();      // done reading P0
    __builtin_amdgcn_sched_barrier(0);
    ISSUE(64, 4, 0)       // p5: s4 kb4-7 -> P0
    __builtin_amdgcn_sched_barrier(0);
    ASM_VMCNT(4);                      // p4 landed
    __builtin_amdgcn_s_barrier();

    // C4: stage4 first half
    SACC_INIT(sacc)
    HALF(sacc, 4, 0, P1, 0)            // s4 kb0-3 @P1 slots 0..15

    __builtin_amdgcn_s_barrier();      // done reading P1
    __builtin_amdgcn_sched_barrier(0);
    ISSUE(80, 3, P1)      // p6: head (12 slots incl pad) -> P1
    __builtin_amdgcn_sched_barrier(0);
    ASM_VMCNT(3);                      // p5 landed
    __builtin_amdgcn_s_barrier();

    // C5: stage4 finish
    HALF(sacc, 4, 4, 0, 0)             // s4 kb4-7 @P0 slots 0..15
    FINISH(sacc, B5 + b * 64, 8)

    ASM_VMCNT(0);                      // p6 landed
    __builtin_amdgcn_s_barrier();

    // ================= head (M=16 padded, K=320) ============================
    f32x4 hacc;
    #pragma unroll
    for (int rr = 0; rr < 4; ++rr) hacc[rr] = 0.f;
    #pragma unroll
    for (int kb = 0; kb < 10; ++kb) {
        const int so = P1 + kb * 1024 + lane8;
        bf16x8 ah = *(const bf16x8*)&wlds[so];
        bf16x8 al = *(const bf16x8*)&wlds[so + 512];
        hacc = MFMA(ah, act_h[kb], hacc);
        hacc = MFMA(ah, act_l[kb], hacc);
        hacc = MFMA(al, act_h[kb], hacc);
    }
    #pragma unroll
    for (int rr = 0; rr < 4; ++rr) {
        const float h0 = B6[b * 8 + rr];
        const float h1 = B6[b * 8 + 4 + rr];
        hacc[rr] += (kq == 0) ? h0 : ((kq == 1) ? h1 : 0.f);
    }

    // ================= epilogue: shuffle + inv-rot + round(tanh*127) ========
    #pragma unroll
    for (int rr = 0; rr < 4; ++rr) {
        const int ch = kq * 4 + rr;
        if (ch < 8) {
            const int oc = ch >> 2;
            const int a  = (ch >> 1) & 1;
            const int bb = ch & 1;
            const int ip = 2 * row + a;
            const int jp = 2 * px + bb;
            int I, J;
            if      (r == 0) { I = ip;       J = jp;       }
            else if (r == 1) { I = jp;       J = 127 - ip; }
            else if (r == 2) { I = 127 - ip; J = 127 - jp; }
            else             { I = 127 - jp; J = ip;       }
            const float v = rintf(tanhf(hacc[rr]) * 127.0f);
            atomicAdd(out + (((batch * 2 + oc) << 14) + I * 128 + J), v * 0.5f);
        }
    }
}

extern "C" void kernel_launch(void* const* d_in, const int* in_sizes, int n_in,
                              void* d_out, int out_size, void* d_ws, size_t ws_size,
                              hipStream_t stream) {
    const float* x   = (const float*)d_in[0];
    const float* pxv = (const float*)d_in[1];
    const float* W1  = (const float*)d_in[2];
    const float* B1  = (const float*)d_in[3];
    const float* W2  = (const float*)d_in[4];
    const float* B2  = (const float*)d_in[5];
    const float* W3  = (const float*)d_in[6];
    const float* B3  = (const float*)d_in[7];
    const float* W4  = (const float*)d_in[8];
    const float* B4  = (const float*)d_in[9];
    const float* W5  = (const float*)d_in[10];
    const float* B5  = (const float*)d_in[11];
    const float* W6  = (const float*)d_in[12];
    const float* B6  = (const float*)d_in[13];
    float* out = (float*)d_out;

    short* wsw = (short*)d_ws;                       // 6 * 94208 shorts (1.13MB)
    float* w1p = (float*)(wsw + 6 * 94208);          // 6912 floats

    prep_weights<<<dim3(63), dim3(256), 0, stream>>>(W1, W2, W3, W4, W5, W6,
                                                     wsw, w1p, out);
    mulut_main<<<dim3(1536), dim3(512), 0, stream>>>(
        x, pxv, B1, B2, B3, B4, B5, B6, wsw, w1p, out);
}